// Round 2
// baseline (74.941 us; speedup 1.0000x reference)
//
#include <hip/hip_runtime.h>
#include <hip/hip_fp16.h>
#include <cstdint>
#include <cstddef>

// Problem shape (fixed by the reference):
//   x: (B=1024, D=512) f32, w: (L=512, D=512) f32, out: (B=1024, L=512) f32
//   out[b,l] = min_d max(x[b,d], 1 - clip(w[l,d],0,1))
// Strategy: packed fp16 (v_pk_min/max_f16) tropical matmul.
//   threshold is 3.05e-3; fp16 rounding error <= 2^-11 ~ 4.9e-4 (min/max exact).
// ROCm's fp16 header lacks __hmin2/__hmax2 -> use native _Float16 vectors +
// __builtin_elementwise_min/max (lowers to v_pk_min_f16 / v_pk_max_f16).

typedef _Float16 h2 __attribute__((ext_vector_type(2)));

static __device__ __forceinline__ h2 pkmin(h2 a, h2 b) {
  return __builtin_elementwise_min(a, b);
}
static __device__ __forceinline__ h2 pkmax(h2 a, h2 b) {
  return __builtin_elementwise_max(a, b);
}

constexpr int Dv = 512;
constexpr int Lv = 512;
constexpr int Bv = 1024;
constexpr int XS_PITCH = 20;  // h2 per xs row: 16 used + 4 pad (80B = 16*5 keeps b128 align)
constexpr int TP = 66;        // prep LDS tile pitch in halves (bank-spread, 4B-align)

struct alignas(16) H2x4 { h2 a, b, c, d; };
struct alignas(8)  H2x2 { h2 a, b; };

// ---------------------------------------------------------------------------
// Prep: build d-major fp16 operands in workspace.
//   xT2[d][bp]  (512 x 512 h2): (x[2bp][d], x[2bp+1][d])
//   cdup[d][l]  (512 x 512 h2): (c, c), c = 1 - clip(w[l][d],0,1)
// blocks 0..127: x tiles (16 b-tiles x 8 d-tiles of 64x64)
// blocks 128..191: w tiles (8 l-tiles x 8 d-tiles of 64x64)
// ---------------------------------------------------------------------------
__global__ __launch_bounds__(256) void prep_transpose(
    const float* __restrict__ x, const float* __restrict__ w,
    h2* __restrict__ xT2, h2* __restrict__ cdup)
{
  __shared__ _Float16 tile[64 * TP];
  const int bid = blockIdx.x;
  const int t   = threadIdx.x;
  const bool isX = bid < 128;
  const float* src;
  int row0, d0;
  if (isX) {
    row0 = (bid & 15) * 64; d0 = (bid >> 4) * 64; src = x;
  } else {
    const int tb = bid - 128;
    row0 = (tb & 7) * 64; d0 = (tb >> 3) * 64; src = w;
  }

  // Phase A: coalesced f32 reads -> fp16 LDS tile[row][d]
  const int r0 = t >> 4;
  const int c4 = (t & 15) * 4;
  #pragma unroll
  for (int r = 0; r < 4; ++r) {
    const int rl = r0 + r * 16;
    float4 v = *(const float4*)(src + (size_t)(row0 + rl) * Dv + d0 + c4);
    if (!isX) {
      v.x = 1.f - fminf(fmaxf(v.x, 0.f), 1.f);
      v.y = 1.f - fminf(fmaxf(v.y, 0.f), 1.f);
      v.z = 1.f - fminf(fmaxf(v.z, 0.f), 1.f);
      v.w = 1.f - fminf(fmaxf(v.w, 0.f), 1.f);
    }
    _Float16* tp = &tile[rl * TP + c4];
    tp[0] = (_Float16)v.x;
    tp[1] = (_Float16)v.y;
    tp[2] = (_Float16)v.z;
    tp[3] = (_Float16)v.w;
  }
  __syncthreads();

  // Phase B: transposed, packed writes
  const int d_loc = t >> 2;
  const int g     = t & 3;
  if (isX) {
    h2 ov[8];
    #pragma unroll
    for (int k = 0; k < 8; ++k) {
      const int bp = g * 8 + k;
      ov[k] = h2{tile[(2 * bp) * TP + d_loc], tile[(2 * bp + 1) * TP + d_loc]};
    }
    h2* dst = xT2 + (size_t)(d0 + d_loc) * (Bv / 2) + (row0 >> 1) + g * 8;
    *(H2x4*)(dst + 0) = *(H2x4*)&ov[0];
    *(H2x4*)(dst + 4) = *(H2x4*)&ov[4];
  } else {
    h2 ov[16];
    #pragma unroll
    for (int k = 0; k < 16; ++k) {
      const _Float16 hv = tile[(g * 16 + k) * TP + d_loc];
      ov[k] = h2{hv, hv};
    }
    h2* dst = cdup + (size_t)(d0 + d_loc) * Lv + row0 + g * 16;
    *(H2x4*)(dst + 0)  = *(H2x4*)&ov[0];
    *(H2x4*)(dst + 4)  = *(H2x4*)&ov[4];
    *(H2x4*)(dst + 8)  = *(H2x4*)&ov[8];
    *(H2x4*)(dst + 12) = *(H2x4*)&ov[12];
  }
}

// ---------------------------------------------------------------------------
// Main: block tile 32b x 32l, 512 threads = 8 waves, split-D (wave w owns
// d in [w*64, w*64+64)). Per-lane 4b x 4l -> 8 h2 accumulators.
// x-frag from LDS (staged once, 40KB padded), c-frag from global (L1/L2).
// Tree-reduce split-D partials through LDS; coalesced f32 stores.
// ---------------------------------------------------------------------------
__global__ __launch_bounds__(512, 4) void softand_main(
    const h2* __restrict__ xT2, const h2* __restrict__ cdup,
    float* __restrict__ out)
{
  __shared__ h2 xs[Dv * XS_PITCH];  // 40 KB
  __shared__ h2 red[2048];          // 8 KB

  const int t  = threadIdx.x;
  const int bx = blockIdx.x;  // 32 b-tiles of 32
  const int by = blockIdx.y;  // 16 l-tiles of 32

  // Stage x panel: xs[d][bp_loc] = xT2[d][bx*16 + bp_loc], bp_loc in [0,16)
  {
    const int q  = t & 3;        // 16B chunk within 64B row
    const int dr = t >> 2;       // 128 rows per pass
    #pragma unroll
    for (int pass = 0; pass < 4; ++pass) {
      const int d = dr + pass * 128;
      H2x4 v = *(const H2x4*)(xT2 + (size_t)d * (Bv / 2) + bx * 16 + q * 4);
      *(H2x4*)(&xs[d * XS_PITCH + q * 4]) = v;
    }
  }
  __syncthreads();

  const int wave = t >> 6;
  const int lane = t & 63;
  const int lg = lane >> 3;  // l-group: 4 l each
  const int bg = lane & 7;   // b-group: 2 h2 (4 b) each

  const h2 hinit = h2{(_Float16)65504.f, (_Float16)65504.f};
  h2 acc[8];  // acc[l_i*2 + p]
  #pragma unroll
  for (int k = 0; k < 8; ++k) acc[k] = hinit;

  const h2* cbase = cdup + by * 32 + lg * 4;
  const int d0w = wave * 64;

  #pragma unroll 8
  for (int i = 0; i < 64; ++i) {
    const int d = d0w + i;
    H2x4 cr = *(const H2x4*)(cbase + (size_t)d * Lv);
    H2x2 xv = *(const H2x2*)(&xs[d * XS_PITCH + bg * 2]);
    acc[0] = pkmin(acc[0], pkmax(xv.a, cr.a));
    acc[1] = pkmin(acc[1], pkmax(xv.b, cr.a));
    acc[2] = pkmin(acc[2], pkmax(xv.a, cr.b));
    acc[3] = pkmin(acc[3], pkmax(xv.b, cr.b));
    acc[4] = pkmin(acc[4], pkmax(xv.a, cr.c));
    acc[5] = pkmin(acc[5], pkmax(xv.b, cr.c));
    acc[6] = pkmin(acc[6], pkmax(xv.a, cr.d));
    acc[7] = pkmin(acc[7], pkmax(xv.b, cr.d));
  }

  // Split-D tree reduction across 8 waves (layout red[(slot*8+k)*64+lane])
  for (int s = 4; s >= 1; s >>= 1) {
    if (wave >= s && wave < 2 * s) {
      #pragma unroll
      for (int k = 0; k < 8; ++k) red[((wave - s) * 8 + k) * 64 + lane] = acc[k];
    }
    __syncthreads();
    if (wave < s) {
      #pragma unroll
      for (int k = 0; k < 8; ++k)
        acc[k] = pkmin(acc[k], red[(wave * 8 + k) * 64 + lane]);
    }
    __syncthreads();
  }

  // Publish final tile from wave 0, then coalesced f32 store by all threads
  if (wave == 0) {
    #pragma unroll
    for (int k = 0; k < 8; ++k) red[k * 64 + lane] = acc[k];
  }
  __syncthreads();

  const int b_loc = t >> 4;          // [0,32)
  const int lp    = t & 15;
  const int l_loc = lp * 2;          // even l within tile
  const int bg2 = b_loc >> 2;
  const int p   = (b_loc >> 1) & 1;
  const int h   = b_loc & 1;
  const int lg2 = l_loc >> 2;
  const int li  = l_loc & 3;         // 0 or 2
  const int lane_src = lg2 * 8 + bg2;
  const h2 v0 = red[(li * 2 + p) * 64 + lane_src];
  const h2 v1 = red[((li + 1) * 2 + p) * 64 + lane_src];
  const _Float16 a0 = h ? v0.y : v0.x;
  const _Float16 a1 = h ? v1.y : v1.x;
  float2 o;
  o.x = (float)a0;
  o.y = (float)a1;
  *(float2*)(out + (size_t)(bx * 32 + b_loc) * Lv + by * 32 + l_loc) = o;
}

// ---------------------------------------------------------------------------
// Fallback (only if workspace is too small): naive exact f32.
// ---------------------------------------------------------------------------
__global__ __launch_bounds__(256) void softand_naive(
    const float* __restrict__ x, const float* __restrict__ w,
    float* __restrict__ out)
{
  const int i = blockIdx.x * 256 + threadIdx.x;
  if (i >= Bv * Lv) return;
  const int b = i >> 9;
  const int l = i & (Lv - 1);
  float m = 1e30f;
  for (int d = 0; d < Dv; ++d) {
    const float c = 1.f - fminf(fmaxf(w[(size_t)l * Dv + d], 0.f), 1.f);
    m = fminf(m, fmaxf(x[(size_t)b * Dv + d], c));
  }
  out[i] = m;
}

extern "C" void kernel_launch(void* const* d_in, const int* in_sizes, int n_in,
                              void* d_out, int out_size, void* d_ws, size_t ws_size,
                              hipStream_t stream) {
  const float* x = (const float*)d_in[0];
  const float* w = (const float*)d_in[1];
  float* out = (float*)d_out;

  const size_t need = (size_t)2 * 512 * 512 * sizeof(h2);  // 2 MB
  if (ws_size < need) {
    softand_naive<<<(Bv * Lv + 255) / 256, 256, 0, stream>>>(x, w, out);
    return;
  }

  h2* xT2  = (h2*)d_ws;                  // 512 x 512 h2 (1 MB)
  h2* cdup = xT2 + (size_t)512 * 512;    // 512 x 512 h2 (1 MB)

  prep_transpose<<<192, 256, 0, stream>>>(x, w, xT2, cdup);
  softand_main<<<dim3(32, 16), 512, 0, stream>>>(xT2, cdup, out);
}

// Round 3
// 69.864 us; speedup vs baseline: 1.0727x; 1.0727x over previous
//
#include <hip/hip_runtime.h>
#include <cstdint>
#include <cstddef>

// out[b,l] = min_d max(x[b,d], 1 - clip(w[l,d],0,1)),  B=1024, L=512, D=512, f32.
// Fused single kernel, packed fp16 (v_pk_min/max_f16) tropical matmul.
// Key trick: pack the D dimension into the fp16x2 SIMD lanes (acc.x = even d,
// acc.y = odd d; final = min(acc.x, acc.y)). Both operands are d-major in
// memory, so NO transpose is ever needed and NO workspace is used (avoids the
// harness's 268 MB d_ws re-poison fill entirely).
//
// Block: 32b x 32l tile, 512 threads = 8 waves, split-D (wave w owns d in
// [64w, 64w+64)). Each wave self-stages its own d-window (f32 -> fp16) into
// LDS for all 32 rows of both operands -- no barrier before compute.
// LDS layout: [row][d] with XOR swizzle on the 16B-block index low bits,
// keyed by (row>>2)&7, making the per-instruction b128 read pattern
// (8 distinct rows x 8-way broadcast) conflict-free with ZERO padding
// (total LDS = exactly 64 KB -> 2 blocks/CU, 16 waves/CU).
// Per lane: 4b x 4l outputs; per 8-d step: 8 x b128 LDS reads + 128 pk ops.
// Split-D partials tree-reduced through LDS (region reused from xs).

typedef _Float16 h2 __attribute__((ext_vector_type(2)));
typedef _Float16 h4 __attribute__((ext_vector_type(4)));
typedef _Float16 h8 __attribute__((ext_vector_type(8)));

constexpr int Dv = 512;
constexpr int Lv = 512;

static __device__ __forceinline__ h8 max8(h8 a, h8 b) { return __builtin_elementwise_max(a, b); }
static __device__ __forceinline__ h4 min4(h4 a, h4 b) { return __builtin_elementwise_min(a, b); }
static __device__ __forceinline__ h2 min2(h2 a, h2 b) { return __builtin_elementwise_min(a, b); }

__global__ __launch_bounds__(512, 4) void softand_fused(
    const float* __restrict__ x, const float* __restrict__ w,
    float* __restrict__ out)
{
  // Two 32x512 fp16 planes, 32 KB each -> 64 KB total. Swizzled, no pad.
  __shared__ _Float16 smem[2 * 32 * 512] __attribute__((aligned(16)));
  _Float16* xs = smem;
  _Float16* cs = smem + 32 * 512;

  const int t    = threadIdx.x;
  const int wave = t >> 6;
  const int lane = t & 63;
  const int bx = blockIdx.x >> 4;   // [0,32) b-tile
  const int by = blockIdx.x & 15;   // [0,16) l-tile (blockIdx%8 = by%8 -> same-by blocks share an XCD)
  const int b0 = bx * 32, l0 = by * 32;

  // -------- Per-wave staging of this wave's 64-d window, all 32 rows, both operands
  // LDS half-index: row*512 + (wave*64 + (blk3 ^ ((row>>2)&7))*8) + off
  #pragma unroll
  for (int k = 0; k < 8; ++k) {
    const int c   = k * 64 + lane;      // [0,512)
    const int row = c >> 4;             // [0,32)
    const int dq  = c & 15;             // [0,16) -> d offset dq*4 within window
    const int blk3 = (dq >> 1) ^ ((row >> 2) & 7);
    const int idx  = row * 512 + wave * 64 + blk3 * 8 + (dq & 1) * 4;

    const float4 vx = *(const float4*)(x + (size_t)(b0 + row) * Dv + wave * 64 + dq * 4);
    h4 hx = { (_Float16)vx.x, (_Float16)vx.y, (_Float16)vx.z, (_Float16)vx.w };
    *(h4*)(&xs[idx]) = hx;

    const float4 vw = *(const float4*)(w + (size_t)(l0 + row) * Dv + wave * 64 + dq * 4);
    h4 hc = { (_Float16)(1.f - fminf(fmaxf(vw.x, 0.f), 1.f)),
              (_Float16)(1.f - fminf(fmaxf(vw.y, 0.f), 1.f)),
              (_Float16)(1.f - fminf(fmaxf(vw.z, 0.f), 1.f)),
              (_Float16)(1.f - fminf(fmaxf(vw.w, 0.f), 1.f)) };
    *(h4*)(&cs[idx]) = hc;
  }
  // No __syncthreads: each wave reads back exactly (and only) what it wrote;
  // the compiler's lgkmcnt waits order the wave-local LDS RAW.

  // -------- Compute: lane tile 4b x 4l, acc packs (even d, odd d)
  const int bg = lane >> 3;   // [0,8) b-group
  const int lg = lane & 7;    // [0,8) l-group
  const int rb = bg * 4;
  const int rl = lg * 4;

  const h2 hinit = h2{(_Float16)65504.f, (_Float16)65504.f};
  h2 acc[16];
  #pragma unroll
  for (int o = 0; o < 16; ++o) acc[o] = hinit;

  const int xbase = wave * 64;
  #pragma unroll 2
  for (int s = 0; s < 8; ++s) {
    h8 xv[4], cv[4];
    #pragma unroll
    for (int i = 0; i < 4; ++i)
      xv[i] = *(const h8*)(&xs[(rb + i) * 512 + xbase + ((s ^ bg) * 8)]);
    #pragma unroll
    for (int j = 0; j < 4; ++j)
      cv[j] = *(const h8*)(&cs[(rl + j) * 512 + xbase + ((s ^ lg) * 8)]);
    #pragma unroll
    for (int i = 0; i < 4; ++i) {
      #pragma unroll
      for (int j = 0; j < 4; ++j) {
        const h8 t8 = max8(xv[i], cv[j]);
        const h4 lo = __builtin_shufflevector(t8, t8, 0, 1, 2, 3);
        const h4 hi = __builtin_shufflevector(t8, t8, 4, 5, 6, 7);
        const h4 m4 = min4(lo, hi);
        const h2 l2 = __builtin_shufflevector(m4, m4, 0, 1);
        const h2 h2v = __builtin_shufflevector(m4, m4, 2, 3);
        acc[i * 4 + j] = min2(acc[i * 4 + j], min2(l2, h2v));
      }
    }
  }

  // -------- Finalize pairs -> 8 packed h2 (two adjacent-l outputs per h2)
  h2 fin[8];
  #pragma unroll
  for (int i = 0; i < 4; ++i) {
    #pragma unroll
    for (int jp = 0; jp < 2; ++jp) {
      const h2 a0 = acc[i * 4 + jp * 2];
      const h2 a1 = acc[i * 4 + jp * 2 + 1];
      const _Float16 m0 = a0.x < a0.y ? a0.x : a0.y;
      const _Float16 m1 = a1.x < a1.y ? a1.x : a1.y;
      fin[i * 2 + jp] = h2{m0, m1};
    }
  }

  // -------- Split-D tree reduction across 8 waves (red overlays xs region)
  __syncthreads();  // all waves done reading LDS planes
  h2* red = (h2*)smem;  // needs 4 slots * 8 * 64 h2 = 8 KB
  for (int s = 4; s >= 1; s >>= 1) {
    if (wave >= s && wave < 2 * s) {
      #pragma unroll
      for (int k = 0; k < 8; ++k) red[((wave - s) * 8 + k) * 64 + lane] = fin[k];
    }
    __syncthreads();
    if (wave < s) {
      #pragma unroll
      for (int k = 0; k < 8; ++k)
        fin[k] = min2(fin[k], red[(wave * 8 + k) * 64 + lane]);
    }
    __syncthreads();
  }

  // -------- Store (wave 0 holds the tile): 8 float2 per lane
  if (wave == 0) {
    #pragma unroll
    for (int i = 0; i < 4; ++i) {
      #pragma unroll
      for (int jp = 0; jp < 2; ++jp) {
        const h2 v = fin[i * 2 + jp];
        float2 o;
        o.x = (float)v.x;
        o.y = (float)v.y;
        *(float2*)(out + (size_t)(b0 + rb + i) * Lv + l0 + rl + jp * 2) = o;
      }
    }
  }
}

extern "C" void kernel_launch(void* const* d_in, const int* in_sizes, int n_in,
                              void* d_out, int out_size, void* d_ws, size_t ws_size,
                              hipStream_t stream) {
  const float* x = (const float*)d_in[0];
  const float* w = (const float*)d_in[1];
  float* out = (float*)d_out;
  (void)d_ws; (void)ws_size; (void)in_sizes; (void)n_in; (void)out_size;

  softand_fused<<<512, 512, 0, stream>>>(x, w, out);
}